// Round 1
// baseline (365.781 us; speedup 1.0000x reference)
//
#include <hip/hip_runtime.h>

#define H_ 256
#define P_ 16
#define KOCC 8
#define KSUBJ 16
#define O_ 128
#define CAPMAX 2048

typedef __attribute__((ext_vector_type(8))) __bf16 bf16x8;
typedef __attribute__((ext_vector_type(4))) float f32x4;

__device__ __forceinline__ bf16x8 load_bf8(const float* p) {
  float4 a = *(const float4*)p;
  float4 b = *(const float4*)(p + 4);
  bf16x8 r;
  r[0] = (__bf16)a.x; r[1] = (__bf16)a.y; r[2] = (__bf16)a.z; r[3] = (__bf16)a.w;
  r[4] = (__bf16)b.x; r[5] = (__bf16)b.y; r[6] = (__bf16)b.z; r[7] = (__bf16)b.w;
  return r;
}

__device__ __forceinline__ float rmax16(float v) {
  v = fmaxf(v, __shfl_xor(v, 1));
  v = fmaxf(v, __shfl_xor(v, 2));
  v = fmaxf(v, __shfl_xor(v, 4));
  v = fmaxf(v, __shfl_xor(v, 8));
  return v;
}
__device__ __forceinline__ float rsum16(float v) {
  v += __shfl_xor(v, 1);
  v += __shfl_xor(v, 2);
  v += __shfl_xor(v, 4);
  v += __shfl_xor(v, 8);
  return v;
}

// Pass 1: bucket rows by global occurrence id (phase*8 + occ_local).
__global__ void scatter_kernel(const int* __restrict__ xp, const int* __restrict__ xo,
                               int* counts, int* brows, int n, int cap) {
  int i = blockIdx.x * blockDim.x + threadIdx.x;
  if (i >= n) return;
  int b = xp[i] * KOCC + xo[i];
  int pos = atomicAdd(&counts[b], 1);
  if (pos < cap) brows[b * cap + pos] = i;
}

// Pass 2: per-bucket MFMA. Block = (bucket, chunk-of-256-rows), 4 waves.
// Each wave handles 4 groups of 16 rows: A from global (coalesced, bf16),
// B (48 weight rows: 16 phase + 8 occ + pad + 16 subj) preloaded in VGPRs.
__global__ __launch_bounds__(256) void hsm_main(
    const float* __restrict__ X,
    const float* __restrict__ Wp, const float* __restrict__ bp,
    const float* __restrict__ Wo, const float* __restrict__ bo,
    const float* __restrict__ Ws, const float* __restrict__ bs,
    const int* __restrict__ subj,
    const int* __restrict__ counts, const int* __restrict__ brows,
    float* __restrict__ out, int n, int cap) {
  int b = blockIdx.x >> 3;       // bucket (global occurrence id)
  int chunk = blockIdx.x & 7;    // which 256-row chunk of the bucket
  int count = counts[b];
  if (count > cap) count = cap;
  int start = chunk * 256;
  if (start >= count) return;
  int p = b >> 3;                // phase of this bucket
  int occl = b & 7;              // local occurrence (softmax target, bucket-uniform)
  int lane = threadIdx.x & 63;
  int wave = threadIdx.x >> 6;
  int col = lane & 15;           // MFMA n-index (class within tile) / A m-index (row)
  int quad = lane >> 4;          // k = quad*8 + j

  // --- Preload B fragments (weights) into registers, once per block ---
  const float* w0 = Wp + col * H_;
  const float* w1 = Wo + (p * KOCC + (col & 7)) * H_;   // cols 8..15 are pad (masked later)
  const float* w2 = Ws + (b * KSUBJ + col) * H_;
  bf16x8 bf0[8], bf1[8], bf2[8];
#pragma unroll
  for (int kk = 0; kk < 8; ++kk) {
    int off = kk * 32 + quad * 8;
    bf0[kk] = load_bf8(w0 + off);
    bf1[kk] = load_bf8(w1 + off);
    bf2[kk] = load_bf8(w2 + off);
  }
  bool v1 = col < KOCC;
  float bias0 = bp[col];
  float bias1 = v1 ? bo[p * KOCC + col] : 0.0f;
  float bias2 = bs[b * KSUBJ + col];

  const int* brow_b = brows + b * cap;

  for (int g = 0; g < 4; ++g) {
    int base = start + wave * 64 + g * 16;
    if (base >= count) break;
    int rem = count - base;      // rows valid in this 16-group (>=1)
    int ra_idx = base + (col < rem ? col : rem - 1);  // clamp duplicates, masked at store
    int rida = brow_b[ra_idx];
    const float* xr = X + (size_t)rida * H_;
    f32x4 acc0 = {0.f, 0.f, 0.f, 0.f};
    f32x4 acc1 = {0.f, 0.f, 0.f, 0.f};
    f32x4 acc2 = {0.f, 0.f, 0.f, 0.f};
#pragma unroll
    for (int kk = 0; kk < 8; ++kk) {
      bf16x8 a = load_bf8(xr + kk * 32 + quad * 8);
      acc0 = __builtin_amdgcn_mfma_f32_16x16x32_bf16(a, bf0[kk], acc0, 0, 0, 0);
      acc1 = __builtin_amdgcn_mfma_f32_16x16x32_bf16(a, bf1[kk], acc1, 0, 0, 0);
      acc2 = __builtin_amdgcn_mfma_f32_16x16x32_bf16(a, bf2[kk], acc2, 0, 0, 0);
    }
    // --- Epilogue: per-row softmax over 16 lanes (D: row = quad*4+r, col = lane&15) ---
#pragma unroll
    for (int r = 0; r < 4; ++r) {
      int rloc = quad * 4 + r;
      bool rv = rloc < rem;
      int ridr = brow_b[base + (rv ? rloc : 0)];   // uniform within the 16-lane group
      int tsub = subj[ridr];
      // phase head (target = p, bucket-uniform)
      float l0 = acc0[r] + bias0;
      float m0 = rmax16(l0);
      float e0 = __expf(l0 - m0);
      float s0 = rsum16(e0);
      float p0 = __shfl(e0, quad * 16 + p) / s0;
      // occurrence head (8 valid cols, target = occl)
      float l1 = v1 ? (acc1[r] + bias1) : -3.0e38f;
      float m1 = rmax16(l1);
      float e1 = v1 ? __expf(l1 - m1) : 0.0f;
      float s1 = rsum16(e1);
      float p1 = __shfl(e1, quad * 16 + occl) / s1;
      // subject head (target = per-row)
      float l2 = acc2[r] + bias2;
      float m2 = rmax16(l2);
      float e2 = __expf(l2 - m2);
      float s2 = rsum16(e2);
      float p2 = __shfl(e2, quad * 16 + tsub) / s2;
      if (col == 0 && rv) {
        float po = p0 * p1;
        out[ridr] = p0;
        out[n + ridr] = po;
        out[2 * n + ridr] = po * p2;
      }
    }
  }
}

extern "C" void kernel_launch(void* const* d_in, const int* in_sizes, int n_in,
                              void* d_out, int out_size, void* d_ws, size_t ws_size,
                              hipStream_t stream) {
  const float* X  = (const float*)d_in[0];
  const float* Wp = (const float*)d_in[1];
  const float* bp = (const float*)d_in[2];
  const float* Wo = (const float*)d_in[3];
  const float* bo = (const float*)d_in[4];
  const float* Ws = (const float*)d_in[5];
  const float* bs = (const float*)d_in[6];
  const int* xp   = (const int*)d_in[7];
  const int* xo   = (const int*)d_in[8];
  const int* xs   = (const int*)d_in[9];
  float* out = (float*)d_out;
  int n = in_sizes[7];

  int* wsI = (int*)d_ws;
  int* counts = wsI;            // 128 ints
  int* brows = wsI + 128;       // 128 * cap ints
  long avail = (long)(ws_size / 4) - 128;
  int cap = (int)(avail / O_);
  if (cap > CAPMAX) cap = CAPMAX;
  if (cap < 1) cap = 1;

  hipMemsetAsync(counts, 0, O_ * sizeof(int), stream);
  scatter_kernel<<<dim3((n + 255) / 256), dim3(256), 0, stream>>>(xp, xo, counts, brows, n, cap);
  hsm_main<<<dim3(O_ * 8), dim3(256), 0, stream>>>(X, Wp, bp, Wo, bo, Ws, bs, xs,
                                                   counts, brows, out, n, cap);
}

// Round 2
// 266.263 us; speedup vs baseline: 1.3738x; 1.3738x over previous
//
#include <hip/hip_runtime.h>

#define H_ 256
#define P_ 16
#define KOCC 8
#define KSUBJ 16
#define O_ 128
#define CAPMAX 2048

typedef __attribute__((ext_vector_type(8))) __bf16 bf16x8;
typedef __attribute__((ext_vector_type(4))) float f32x4;

__device__ __forceinline__ bf16x8 load_bf8(const float* p) {
  float4 a = *(const float4*)p;
  float4 b = *(const float4*)(p + 4);
  bf16x8 r;
  r[0] = (__bf16)a.x; r[1] = (__bf16)a.y; r[2] = (__bf16)a.z; r[3] = (__bf16)a.w;
  r[4] = (__bf16)b.x; r[5] = (__bf16)b.y; r[6] = (__bf16)b.z; r[7] = (__bf16)b.w;
  return r;
}

__device__ __forceinline__ float rmax16(float v) {
  v = fmaxf(v, __shfl_xor(v, 1));
  v = fmaxf(v, __shfl_xor(v, 2));
  v = fmaxf(v, __shfl_xor(v, 4));
  v = fmaxf(v, __shfl_xor(v, 8));
  return v;
}
__device__ __forceinline__ float rsum16(float v) {
  v += __shfl_xor(v, 1);
  v += __shfl_xor(v, 2);
  v += __shfl_xor(v, 4);
  v += __shfl_xor(v, 8);
  return v;
}

// Pass 1: bucket rows by global occurrence id, LDS-histogram aggregated.
// One global atomic per (block,bucket) instead of per row: 32768 atomics
// (~256-way parallel) vs 131072 serialized 1024-deep per counter.
__global__ __launch_bounds__(512) void scatter_kernel(
    const int* __restrict__ xp, const int* __restrict__ xo,
    int* counts, int* brows, int n, int cap) {
  __shared__ int hist[O_];
  __shared__ int basev[O_];
  int tid = threadIdx.x;
  if (tid < O_) hist[tid] = 0;
  __syncthreads();
  int i = blockIdx.x * blockDim.x + tid;
  int b = 0, pos = -1;
  if (i < n) {
    b = xp[i] * KOCC + xo[i];
    pos = atomicAdd(&hist[b], 1);   // LDS atomic: ~4-way contention
  }
  __syncthreads();
  if (tid < O_) basev[tid] = atomicAdd(&counts[tid], hist[tid]);  // 1 global atomic per bucket
  __syncthreads();
  if (pos >= 0) {
    int idx = basev[b] + pos;
    if (idx < cap) brows[b * cap + idx] = i;
  }
}

// Pass 2: per-bucket MFMA. Block = (bucket, chunk-of-256-rows), 4 waves.
// Each wave handles 4 groups of 16 rows: A from global (coalesced, bf16),
// B (48 weight rows: 16 phase + 8 occ + pad + 16 subj) preloaded in VGPRs.
__global__ __launch_bounds__(256) void hsm_main(
    const float* __restrict__ X,
    const float* __restrict__ Wp, const float* __restrict__ bp,
    const float* __restrict__ Wo, const float* __restrict__ bo,
    const float* __restrict__ Ws, const float* __restrict__ bs,
    const int* __restrict__ subj,
    const int* __restrict__ counts, const int* __restrict__ brows,
    float* __restrict__ out, int n, int cap) {
  int b = blockIdx.x >> 3;       // bucket (global occurrence id)
  int chunk = blockIdx.x & 7;    // which 256-row chunk of the bucket
  int count = counts[b];
  if (count > cap) count = cap;
  int start = chunk * 256;
  if (start >= count) return;
  int p = b >> 3;                // phase of this bucket
  int occl = b & 7;              // local occurrence (softmax target, bucket-uniform)
  int lane = threadIdx.x & 63;
  int wave = threadIdx.x >> 6;
  int col = lane & 15;           // MFMA n-index (class within tile) / A m-index (row)
  int quad = lane >> 4;          // k = quad*8 + j

  // --- Preload B fragments (weights) into registers, once per block ---
  const float* w0 = Wp + col * H_;
  const float* w1 = Wo + (p * KOCC + (col & 7)) * H_;   // cols 8..15 are pad (masked later)
  const float* w2 = Ws + (b * KSUBJ + col) * H_;
  bf16x8 bf0[8], bf1[8], bf2[8];
#pragma unroll
  for (int kk = 0; kk < 8; ++kk) {
    int off = kk * 32 + quad * 8;
    bf0[kk] = load_bf8(w0 + off);
    bf1[kk] = load_bf8(w1 + off);
    bf2[kk] = load_bf8(w2 + off);
  }
  bool v1 = col < KOCC;
  float bias0 = bp[col];
  float bias1 = v1 ? bo[p * KOCC + col] : 0.0f;
  float bias2 = bs[b * KSUBJ + col];

  const int* brow_b = brows + b * cap;

  for (int g = 0; g < 4; ++g) {
    int base = start + wave * 64 + g * 16;
    if (base >= count) break;
    int rem = count - base;      // rows valid in this 16-group (>=1)
    int ra_idx = base + (col < rem ? col : rem - 1);  // clamp duplicates, masked at store
    int rida = brow_b[ra_idx];
    const float* xr = X + (size_t)rida * H_;
    f32x4 acc0 = {0.f, 0.f, 0.f, 0.f};
    f32x4 acc1 = {0.f, 0.f, 0.f, 0.f};
    f32x4 acc2 = {0.f, 0.f, 0.f, 0.f};
#pragma unroll
    for (int kk = 0; kk < 8; ++kk) {
      bf16x8 a = load_bf8(xr + kk * 32 + quad * 8);
      acc0 = __builtin_amdgcn_mfma_f32_16x16x32_bf16(a, bf0[kk], acc0, 0, 0, 0);
      acc1 = __builtin_amdgcn_mfma_f32_16x16x32_bf16(a, bf1[kk], acc1, 0, 0, 0);
      acc2 = __builtin_amdgcn_mfma_f32_16x16x32_bf16(a, bf2[kk], acc2, 0, 0, 0);
    }
    // --- Epilogue: per-row softmax over 16 lanes (D: row = quad*4+r, col = lane&15) ---
#pragma unroll
    for (int r = 0; r < 4; ++r) {
      int rloc = quad * 4 + r;
      bool rv = rloc < rem;
      int ridr = brow_b[base + (rv ? rloc : 0)];   // uniform within the 16-lane group
      int tsub = subj[ridr];
      // phase head (target = p, bucket-uniform)
      float l0 = acc0[r] + bias0;
      float m0 = rmax16(l0);
      float e0 = __expf(l0 - m0);
      float s0 = rsum16(e0);
      float p0 = __shfl(e0, quad * 16 + p) / s0;
      // occurrence head (8 valid cols, target = occl)
      float l1 = v1 ? (acc1[r] + bias1) : -3.0e38f;
      float m1 = rmax16(l1);
      float e1 = v1 ? __expf(l1 - m1) : 0.0f;
      float s1 = rsum16(e1);
      float p1 = __shfl(e1, quad * 16 + occl) / s1;
      // subject head (target = per-row)
      float l2 = acc2[r] + bias2;
      float m2 = rmax16(l2);
      float e2 = __expf(l2 - m2);
      float s2 = rsum16(e2);
      float p2 = __shfl(e2, quad * 16 + tsub) / s2;
      if (col == 0 && rv) {
        float po = p0 * p1;
        out[ridr] = p0;
        out[n + ridr] = po;
        out[2 * n + ridr] = po * p2;
      }
    }
  }
}

extern "C" void kernel_launch(void* const* d_in, const int* in_sizes, int n_in,
                              void* d_out, int out_size, void* d_ws, size_t ws_size,
                              hipStream_t stream) {
  const float* X  = (const float*)d_in[0];
  const float* Wp = (const float*)d_in[1];
  const float* bp = (const float*)d_in[2];
  const float* Wo = (const float*)d_in[3];
  const float* bo = (const float*)d_in[4];
  const float* Ws = (const float*)d_in[5];
  const float* bs = (const float*)d_in[6];
  const int* xp   = (const int*)d_in[7];
  const int* xo   = (const int*)d_in[8];
  const int* xs   = (const int*)d_in[9];
  float* out = (float*)d_out;
  int n = in_sizes[7];

  int* wsI = (int*)d_ws;
  int* counts = wsI;            // 128 ints
  int* brows = wsI + 128;       // 128 * cap ints
  long avail = (long)(ws_size / 4) - 128;
  int cap = (int)(avail / O_);
  if (cap > CAPMAX) cap = CAPMAX;
  if (cap < 1) cap = 1;

  hipMemsetAsync(counts, 0, O_ * sizeof(int), stream);
  scatter_kernel<<<dim3((n + 511) / 512), dim3(512), 0, stream>>>(xp, xo, counts, brows, n, cap);
  hsm_main<<<dim3(O_ * 8), dim3(256), 0, stream>>>(X, Wp, bp, Wo, bo, Ws, bs, xs,
                                                   counts, brows, out, n, cap);
}

// Round 3
// 245.453 us; speedup vs baseline: 1.4902x; 1.0848x over previous
//
#include <hip/hip_runtime.h>

#define H_ 256
#define P_ 16
#define KOCC 8
#define KSUBJ 16
#define O_ 128
#define CAPMAX 2048

typedef __attribute__((ext_vector_type(8))) __bf16 bf16x8;
typedef __attribute__((ext_vector_type(4))) float f32x4;

__device__ __forceinline__ bf16x8 load_bf8(const float* p) {
  float4 a = *(const float4*)p;
  float4 b = *(const float4*)(p + 4);
  bf16x8 r;
  r[0] = (__bf16)a.x; r[1] = (__bf16)a.y; r[2] = (__bf16)a.z; r[3] = (__bf16)a.w;
  r[4] = (__bf16)b.x; r[5] = (__bf16)b.y; r[6] = (__bf16)b.z; r[7] = (__bf16)b.w;
  return r;
}

__device__ __forceinline__ float rmax16(float v) {
  v = fmaxf(v, __shfl_xor(v, 1));
  v = fmaxf(v, __shfl_xor(v, 2));
  v = fmaxf(v, __shfl_xor(v, 4));
  v = fmaxf(v, __shfl_xor(v, 8));
  return v;
}
__device__ __forceinline__ float rsum16(float v) {
  v += __shfl_xor(v, 1);
  v += __shfl_xor(v, 2);
  v += __shfl_xor(v, 4);
  v += __shfl_xor(v, 8);
  return v;
}

// Pass 1: bucket rows by global occurrence id. 32 blocks x 1024 thr x 4 elems:
// LDS histogram -> 4096 global atomics total, only 32-deep per counter.
__global__ __launch_bounds__(1024) void scatter_kernel(
    const int* __restrict__ xp, const int* __restrict__ xo,
    int* counts, int* brows, int n, int cap) {
  __shared__ int hist[O_];
  __shared__ int basev[O_];
  int tid = threadIdx.x;
  if (tid < O_) hist[tid] = 0;
  __syncthreads();
  int base_i = blockIdx.x * 4096 + tid;
  int be[4], pos[4];
#pragma unroll
  for (int e = 0; e < 4; ++e) {
    int i = base_i + e * 1024;
    pos[e] = -1;
    if (i < n) {
      be[e] = xp[i] * KOCC + xo[i];
      pos[e] = atomicAdd(&hist[be[e]], 1);
    }
  }
  __syncthreads();
  if (tid < O_) basev[tid] = atomicAdd(&counts[tid], hist[tid]);
  __syncthreads();
#pragma unroll
  for (int e = 0; e < 4; ++e) {
    if (pos[e] >= 0) {
      int idx = basev[be[e]] + pos[e];
      if (idx < cap) brows[be[e] * cap + idx] = base_i + e * 1024;
    }
  }
}

// Pass 2: block = (bucket, 64-row chunk), 4 waves, one 16-row MFMA group per
// wave. B fragments (3 heads x 8 k-steps) staged in LDS in exact fragment
// order (16 B/lane stride -> conflict-free ds_read_b128), loaded once/block.
__global__ __launch_bounds__(256) void hsm_main(
    const float* __restrict__ X,
    const float* __restrict__ Wp, const float* __restrict__ bp,
    const float* __restrict__ Wo, const float* __restrict__ bo,
    const float* __restrict__ Ws, const float* __restrict__ bs,
    const int* __restrict__ subj,
    const int* __restrict__ counts, const int* __restrict__ brows,
    float* __restrict__ out, int n, int cap) {
  int b = blockIdx.x >> 5;       // bucket (global occurrence id)
  int chunk = blockIdx.x & 31;   // 64-row chunk
  int count = counts[b];
  if (count > cap) count = cap;
  int start = chunk * 64;
  if (start >= count) return;    // block-uniform exit (before any barrier)
  int p = b >> 3;
  int occl = b & 7;

  // --- Stage B fragments into LDS: [head][kk][lane] x 8 bf16 (16 B) ---
  __shared__ __bf16 Bf[3 * 8 * 64 * 8];  // 24 KB
  {
    int t = threadIdx.x;
#pragma unroll
    for (int it = 0; it < 6; ++it) {
      int fid = it * 256 + t;          // 0..1535
      int lane_f = fid & 63;
      int hk = fid >> 6;               // 0..23
      int head = hk >> 3, kk = hk & 7;
      int colf = lane_f & 15, quadf = lane_f >> 4;
      const float* src;
      if (head == 0)      src = Wp + colf * H_;
      else if (head == 1) src = Wo + (p * KOCC + (colf & 7)) * H_;
      else                src = Ws + (b * KSUBJ + colf) * H_;
      bf16x8 v = load_bf8(src + kk * 32 + quadf * 8);
      *(bf16x8*)&Bf[(size_t)fid * 8] = v;
    }
  }
  __syncthreads();

  int lane = threadIdx.x & 63;
  int wave = threadIdx.x >> 6;
  int col = lane & 15;
  int quad = lane >> 4;

  int base = start + wave * 16;
  if (base >= count) return;     // idle tail wave (after barrier)
  int rem = count - base;        // valid rows in this 16-group

  bool v1 = col < KOCC;
  float bias0 = bp[col];
  float bias1 = v1 ? bo[p * KOCC + col] : 0.0f;
  float bias2 = bs[b * KSUBJ + col];

  const int* brow_b = brows + b * cap;
  int rida = brow_b[base + (col < rem ? col : rem - 1)];
  int subjv = subj[rida];        // lane col holds subj target for local row col
  const float* xr = X + (size_t)rida * H_;

  const bf16x8* Bfrag = (const bf16x8*)Bf;
  f32x4 acc0 = {0.f, 0.f, 0.f, 0.f};
  f32x4 acc1 = {0.f, 0.f, 0.f, 0.f};
  f32x4 acc2 = {0.f, 0.f, 0.f, 0.f};
#pragma unroll
  for (int kk = 0; kk < 8; ++kk) {
    bf16x8 a = load_bf8(xr + kk * 32 + quad * 8);
    acc0 = __builtin_amdgcn_mfma_f32_16x16x32_bf16(a, Bfrag[kk * 64 + lane], acc0, 0, 0, 0);
    acc1 = __builtin_amdgcn_mfma_f32_16x16x32_bf16(a, Bfrag[(8 + kk) * 64 + lane], acc1, 0, 0, 0);
    acc2 = __builtin_amdgcn_mfma_f32_16x16x32_bf16(a, Bfrag[(16 + kk) * 64 + lane], acc2, 0, 0, 0);
  }

  // --- Epilogue: per-row softmax across the 16 lanes of each quad group ---
#pragma unroll
  for (int r = 0; r < 4; ++r) {
    int rloc = quad * 4 + r;
    bool rv = rloc < rem;
    int ridr = __shfl(rida, rloc);     // lane rloc holds row id for local row rloc
    int tsub = __shfl(subjv, rloc);
    // phase head (target = p, bucket-uniform)
    float l0 = acc0[r] + bias0;
    float m0 = rmax16(l0);
    float e0 = __expf(l0 - m0);
    float s0 = rsum16(e0);
    float p0 = __shfl(e0, quad * 16 + p) / s0;
    // occurrence head (8 valid cols, target = occl)
    float l1 = v1 ? (acc1[r] + bias1) : -3.0e38f;
    float m1 = rmax16(l1);
    float e1 = v1 ? __expf(l1 - m1) : 0.0f;
    float s1 = rsum16(e1);
    float p1 = __shfl(e1, quad * 16 + occl) / s1;
    // subject head (target = per-row)
    float l2 = acc2[r] + bias2;
    float m2 = rmax16(l2);
    float e2 = __expf(l2 - m2);
    float s2 = rsum16(e2);
    float p2 = __shfl(e2, quad * 16 + tsub) / s2;
    if (col == 0 && rv) {
      float po = p0 * p1;
      out[ridr] = p0;
      out[n + ridr] = po;
      out[2 * n + ridr] = po * p2;
    }
  }
}

extern "C" void kernel_launch(void* const* d_in, const int* in_sizes, int n_in,
                              void* d_out, int out_size, void* d_ws, size_t ws_size,
                              hipStream_t stream) {
  const float* X  = (const float*)d_in[0];
  const float* Wp = (const float*)d_in[1];
  const float* bp = (const float*)d_in[2];
  const float* Wo = (const float*)d_in[3];
  const float* bo = (const float*)d_in[4];
  const float* Ws = (const float*)d_in[5];
  const float* bs = (const float*)d_in[6];
  const int* xp   = (const int*)d_in[7];
  const int* xo   = (const int*)d_in[8];
  const int* xs   = (const int*)d_in[9];
  float* out = (float*)d_out;
  int n = in_sizes[7];

  int* wsI = (int*)d_ws;
  int* counts = wsI;            // 128 ints
  int* brows = wsI + 128;       // 128 * cap ints
  long avail = (long)(ws_size / 4) - 128;
  int cap = (int)(avail / O_);
  if (cap > CAPMAX) cap = CAPMAX;
  if (cap < 1) cap = 1;

  hipMemsetAsync(counts, 0, O_ * sizeof(int), stream);
  scatter_kernel<<<dim3((n + 4095) / 4096), dim3(1024), 0, stream>>>(xp, xo, counts, brows, n, cap);
  hsm_main<<<dim3(O_ * 32), dim3(256), 0, stream>>>(X, Wp, bp, Wo, bo, Ws, bs, xs,
                                                    counts, brows, out, n, cap);
}